// Round 1
// 246.667 us; speedup vs baseline: 1.0361x; 1.0361x over previous
//
#include <hip/hip_runtime.h>
#include <math.h>

#define NL  1024     // N_LEVELS
#define KP1 9        // K+1
#define NB  4096     // direct-mapped buckets (8 KB u16 table -> 8 blocks/CU)

// d_ws float layout:
//   [0]=lo0  [1]=inv  [2..3] pad
//   [WS_PAIR .. +2064)  float2 pairs {B[i], tab[i]}, i in [0,1032): 1023 real
//                       boundaries, [1023]=INF, 8 INF overrun pads
//   [WS_BKT  .. +2048)  4096 x u16 bucket->start-count table
#define WS_PAIR 4
#define WS_BKT  (WS_PAIR + 2*(NL+8))   // float idx 2068, byte 8272 (16B aligned)

// order-preserving float<->uint map (total order incl. negatives)
__device__ __forceinline__ unsigned oi(float f) {
    unsigned u = __float_as_uint(f);
    return (u & 0x80000000u) ? ~u : (u | 0x80000000u);
}
__device__ __forceinline__ float unoi(unsigned k) {
    return __uint_as_float((k & 0x80000000u) ? (k & 0x7fffffffu) : ~k);
}

// bucket index — MUST be the identical fp32 op sequence in build and main
// kernels (monotone: fp sub/mul-by-positive/trunc/clamp are all monotone).
__device__ __forceinline__ int bidx(float x, float lo0, float inv) {
    float t = (x - lo0) * inv;
    int j = (int)t;              // trunc toward zero; clamped below anyway
    j = j < 0 ? 0 : j;
    j = j > (NB - 1) ? (NB - 1) : j;
    return j;
}

// ---------------------------------------------------------------------------
// Build kernel (1 block, 1024 threads):
//  1. tab[i]  = reference threshold-chain output for level i (exact replica)
//  2. B[i]    = smallest fp32 x where pair (i,i+1) chooses RIGHT, via bit-level
//               binary search of the exact reference predicate !(|x-l|<|x-r|)
//  3. pairs[i] = {B[i], tab[i]}   (scan's terminating read yields the answer)
//  4. bucket[j] = #{ i : bidx(B[i]) < j }   (u16, searchsorted start counts)
// ---------------------------------------------------------------------------
__global__ __launch_bounds__(1024) void build_kernel(
    const float* __restrict__ h, const float* __restrict__ d,
    const float* __restrict__ T, const float* __restrict__ bp,
    float* __restrict__ ws)
{
    __shared__ float s_g[NL];
    __shared__ float s_B[NL];     // 1023 boundaries + [1023]=INF
    __shared__ int   s_jb[NL];    // bidx of each boundary + sentinel
    __shared__ float s_lo0, s_inv;

    const int tid = threadIdx.x;
    float g = h[tid * KP1];
    s_g[tid] = g;

    // 1. out-value table (exact replica of reference fp32 sequence)
    float outv;
    {
        float v = g, o = 0.0f, b = bp[0];
#pragma unroll
        for (int t = 1; t <= 8; ++t) {
            float z = ((v - T[t]) >= 0.0f) ? 1.0f : 0.0f;
            o = o + z * d[t];
            if (t != 8) v = h[tid * KP1 + (t + 1)];
        }
        outv = o - b;
    }
    __syncthreads();

    // 2. exact fp32 decision boundary per adjacent pair
    if (tid < NL - 1) {
        float l = s_g[tid], r = s_g[tid + 1];
        unsigned a = oi(l), b2 = oi(r);   // predicate false at l, true at r
        while (a < b2) {
            unsigned m = a + ((b2 - a) >> 1);
            float xm = unoi(m);
            float dl = fabsf(xm - l), dr = fabsf(xm - r);
            if (!(dl < dr)) b2 = m; else a = m + 1;
        }
        s_B[tid] = unoi(a);
    } else {
        s_B[tid] = INFINITY;
    }
    __syncthreads();

    if (tid == 0) {
        float lo0 = s_B[0];
        float inv = (float)NB / (s_B[NL - 2] - lo0);
        s_lo0 = lo0; s_inv = inv;
        ws[0] = lo0; ws[1] = inv;
    }
    __syncthreads();

    float lo0 = s_lo0, inv = s_inv;
    s_jb[tid] = (tid < NL - 1) ? bidx(s_B[tid], lo0, inv) : 0x7fffffff;

    // 3. interleaved {boundary, value} pairs + overrun pads
    ws[WS_PAIR + 2 * tid]     = s_B[tid];
    ws[WS_PAIR + 2 * tid + 1] = outv;
    if (tid < 8) {
        ws[WS_PAIR + 2 * (NL + tid)]     = INFINITY;
        ws[WS_PAIR + 2 * (NL + tid) + 1] = 0.0f;
    }
    __syncthreads();

    // 4. bucket start counts: lower_bound over sorted s_jb
    unsigned short* bucket = (unsigned short*)(ws + WS_BKT);
    for (int j = tid; j < NB; j += 1024) {
        int lo = 0;
#pragma unroll
        for (int s = 512; s >= 1; s >>= 1)
            if (s_jb[lo + s - 1] < j) lo += s;
        bucket[j] = (unsigned short)lo;
    }
}

// ---------------------------------------------------------------------------
// Main kernel: per element — bucket lookup, then a ~1.1-step scan where the
// terminating ds_read_b64 delivers {boundary, value} together.
// LDS = 8.3 KB pairs + 8 KB buckets ≈ 16.5 KB -> 8 blocks/CU (32 waves, 100%).
// ---------------------------------------------------------------------------
typedef float vf4 __attribute__((ext_vector_type(4)));

__global__ __launch_bounds__(256) void ps_act_kernel(
    const float* __restrict__ x,
    const float* __restrict__ ws,
    float* __restrict__ out,
    int n4)
{
    __shared__ __align__(16) float          spair[2 * (NL + 8)];
    __shared__ __align__(16) unsigned short sbk[NB];

    const int tid = threadIdx.x;
    // vectorized staging: 516 float4s of pairs, 512 uint4s of buckets
    {
        const float4* wp4 = (const float4*)(ws + WS_PAIR);
        float4* sp4 = (float4*)spair;
        for (int i = tid; i < 2 * (NL + 8) / 4; i += 256) sp4[i] = wp4[i];
        const uint4* wb4 = (const uint4*)(ws + WS_BKT);
        uint4* sb4 = (uint4*)sbk;
        for (int i = tid; i < NB * 2 / 16; i += 256) sb4[i] = wb4[i];
    }
    const float lo0 = ws[0];
    const float inv = ws[1];
    __syncthreads();

    const float4* __restrict__ x4 = (const float4*)x;
    float4* __restrict__ o4 = (float4*)out;
    const float2* pp = (const float2*)spair;
    const int stride = gridDim.x * blockDim.x;

    for (int i4 = blockIdx.x * blockDim.x + tid; i4 < n4; i4 += stride) {
        float4 xv = x4[i4];
        float xin[4] = {xv.x, xv.y, xv.z, xv.w};
        float xo[4];
#pragma unroll
        for (int e = 0; e < 4; ++e) {
            float xf = xin[e];
            int j = bidx(xf, lo0, inv);
            int ni = sbk[j];
            float2 pv = pp[ni];
            // avg ~0.13 extra iterations; INF pads guarantee termination
            while (pv.x <= xf) { ++ni; pv = pp[ni]; }
            xo[e] = pv.y;
        }
        // out is write-only: nontemporal store keeps x resident in L2/L3
        vf4 ov = {xo[0], xo[1], xo[2], xo[3]};
        __builtin_nontemporal_store(ov, (vf4*)&o4[i4]);
    }
}

extern "C" void kernel_launch(void* const* d_in, const int* in_sizes, int n_in,
                              void* d_out, int out_size, void* d_ws, size_t ws_size,
                              hipStream_t stream) {
    const float* x = (const float*)d_in[0];
    const float* h = (const float*)d_in[1];
    const float* d = (const float*)d_in[2];
    const float* T = (const float*)d_in[3];
    const float* b = (const float*)d_in[4];
    float* out = (float*)d_out;
    float* ws  = (float*)d_ws;

    int n  = in_sizes[0];
    int n4 = n / 4;

    build_kernel<<<1, 1024, 0, stream>>>(h, d, T, b, ws);
    // 4096 blocks x 256: 8 float4 iters/thread; LDS ~16.5 KB -> 8 blocks/CU
    // (32 waves/CU, full occupancy) for latency hiding.
    ps_act_kernel<<<4096, 256, 0, stream>>>(x, ws, out, n4);
}